// Round 1
// baseline (733.927 us; speedup 1.0000x reference)
//
#include <hip/hip_runtime.h>
#include <hip/hip_bf16.h>

// Problem constants: B=4, S=1024, E=1024, H=16, d=64 -> NH = B*H = 64 heads.
// Output: [64, 1024, 1024] fp32 sparsemax(Q K^T) per head. SCALE = 1.0.

#define DOT4(acc, qv, kv) \
    acc = fmaf((qv).x, (kv).x, fmaf((qv).y, (kv).y, fmaf((qv).z, (kv).z, fmaf((qv).w, (kv).w, acc))))

// ---------------------------------------------------------------------------
// Kernel 1: projection. C[m][c] = sum_e x[m][e] * W[1024+c][e]
//   m in [0,4096)  (b = m>>10, s = m&1023)
//   c in [0,1024) -> K chunk, c in [1024,2048) -> Q chunk
// Stored head-major: kh/qh[n][s][d], n = b*16 + head, d = c&63.
// fp32 tiled GEMM: 128x128 tile, BK=32, 256 threads, 8x8 micro-tile.
// ---------------------------------------------------------------------------
__global__ __launch_bounds__(256)
void proj_kernel(const float* __restrict__ x, const float* __restrict__ w,
                 float* __restrict__ kh, float* __restrict__ qh)
{
    __shared__ __align__(16) float as_[32][132];   // [k][m], padded
    __shared__ __align__(16) float bs_[32][132];   // [k][c], padded
    const int tid = threadIdx.x;
    const int m0 = blockIdx.y * 128;
    const int c0 = blockIdx.x * 128;
    const int tx = tid & 15, ty = tid >> 4;
    const int ar = tid >> 3, ac = (tid & 7) << 2;      // staging coords
    const float* wb = w + (size_t)1024 * 1024;         // rows 1024.. (k then q)

    float acc[8][8];
#pragma unroll
    for (int i = 0; i < 8; ++i)
#pragma unroll
        for (int j = 0; j < 8; ++j) acc[i][j] = 0.f;

    for (int k0 = 0; k0 < 1024; k0 += 32) {
        __syncthreads();   // previous compute done before restaging
#pragma unroll
        for (int i = 0; i < 4; ++i) {
            const int r = ar + 32 * i;
            float4 va = *(const float4*)(x  + (size_t)(m0 + r) * 1024 + k0 + ac);
            as_[ac + 0][r] = va.x; as_[ac + 1][r] = va.y;
            as_[ac + 2][r] = va.z; as_[ac + 3][r] = va.w;
            float4 vb = *(const float4*)(wb + (size_t)(c0 + r) * 1024 + k0 + ac);
            bs_[ac + 0][r] = vb.x; bs_[ac + 1][r] = vb.y;
            bs_[ac + 2][r] = vb.z; bs_[ac + 3][r] = vb.w;
        }
        __syncthreads();
#pragma unroll
        for (int kk = 0; kk < 32; ++kk) {
            float a[8], b[8];
            *(float4*)&a[0] = *(const float4*)&as_[kk][4 * ty];
            *(float4*)&a[4] = *(const float4*)&as_[kk][64 + 4 * ty];
            *(float4*)&b[0] = *(const float4*)&bs_[kk][4 * tx];
            *(float4*)&b[4] = *(const float4*)&bs_[kk][64 + 4 * tx];
#pragma unroll
            for (int i = 0; i < 8; ++i)
#pragma unroll
                for (int j = 0; j < 8; ++j)
                    acc[i][j] = fmaf(a[i], b[j], acc[i][j]);
        }
    }

    // epilogue: scatter to head-major K / Q buffers (float4 along d)
#pragma unroll
    for (int i = 0; i < 8; ++i) {
        const int m = m0 + ((i < 4) ? (4 * ty + i) : (64 + 4 * ty + (i - 4)));
#pragma unroll
        for (int g = 0; g < 2; ++g) {
            const int c = c0 + g * 64 + 4 * tx;
            float4 v = make_float4(acc[i][g * 4 + 0], acc[i][g * 4 + 1],
                                   acc[i][g * 4 + 2], acc[i][g * 4 + 3]);
            float* dst = (c < 1024) ? kh : qh;
            const int cc = c & 1023;
            const int n = ((m >> 10) << 4) + (cc >> 6);
            *(float4*)(dst + ((size_t)n << 16) + ((size_t)(m & 1023) << 6) + (cc & 63)) = v;
        }
    }
}

// ---------------------------------------------------------------------------
// Kernel 2: fused logits GEMM + sparsemax.
// Block = (head n, 32 q-rows). LDS: logits [32][1024] (128KB) + K tile + Q tile.
// GEMM: j-tiles of 64 K-rows, 256 threads, 2x4 micro-tile.
// Sparsemax: wave-per-row Michelot iteration (exact simplex projection),
// fused relu(z - tau) write to global.
// ---------------------------------------------------------------------------
__global__ __launch_bounds__(256)
void attn_sparsemax_kernel(const float* __restrict__ kh, const float* __restrict__ qh,
                           float* __restrict__ out)
{
    __shared__ __align__(16) float lg[32][1024];   // 131072 B
    __shared__ __align__(16) float kt[64][68];     //  17408 B
    __shared__ __align__(16) float qs[32][68];     //   8704 B   total 153.5 KB
    const int tid = threadIdx.x;
    const int n  = blockIdx.x;          // head 0..63
    const int r0 = blockIdx.y * 32;     // q-row base
    const float* Qn = qh + ((size_t)n << 16);
    const float* Kn = kh + ((size_t)n << 16);

    // load Q tile [32 x 64]
    {
        const int rr = tid >> 4, dc = (tid & 15) << 2;
#pragma unroll
        for (int i = 0; i < 2; ++i) {
            float4 v = *(const float4*)(Qn + (size_t)(r0 + rr + 16 * i) * 64 + dc);
            *(float4*)&qs[rr + 16 * i][dc] = v;
        }
    }

    const int tx = tid & 15, ty = tid >> 4;   // cols {tx,+16,+32,+48}, rows {ty, ty+16}
    for (int j0 = 0; j0 < 1024; j0 += 64) {
        __syncthreads();                      // kt free to overwrite
        {
            const int jr = tid >> 4, dc = (tid & 15) << 2;
#pragma unroll
            for (int p = 0; p < 4; ++p) {
                float4 v = *(const float4*)(Kn + (size_t)(j0 + jr + 16 * p) * 64 + dc);
                *(float4*)&kt[jr + 16 * p][dc] = v;
            }
        }
        __syncthreads();                      // kt (and on iter 0, qs) ready

        float acc[2][4] = {{0.f, 0.f, 0.f, 0.f}, {0.f, 0.f, 0.f, 0.f}};
#pragma unroll
        for (int d = 0; d < 64; d += 4) {
            float4 q0 = *(const float4*)&qs[ty][d];
            float4 q1 = *(const float4*)&qs[ty + 16][d];
            float4 k0 = *(const float4*)&kt[tx][d];
            float4 k1 = *(const float4*)&kt[tx + 16][d];
            float4 k2 = *(const float4*)&kt[tx + 32][d];
            float4 k3 = *(const float4*)&kt[tx + 48][d];
            DOT4(acc[0][0], q0, k0); DOT4(acc[0][1], q0, k1);
            DOT4(acc[0][2], q0, k2); DOT4(acc[0][3], q0, k3);
            DOT4(acc[1][0], q1, k0); DOT4(acc[1][1], q1, k1);
            DOT4(acc[1][2], q1, k2); DOT4(acc[1][3], q1, k3);
        }
#pragma unroll
        for (int i = 0; i < 2; ++i)
#pragma unroll
            for (int q = 0; q < 4; ++q)
                lg[ty + 16 * i][j0 + tx + 16 * q] = acc[i][q];
    }
    __syncthreads();   // all logits in LDS

    // --- sparsemax: wave wv handles rows 8*wv .. 8*wv+7 ---
    const int wv = tid >> 6, ln = tid & 63;
    for (int rr = 0; rr < 8; ++rr) {
        const int r = (wv << 3) + rr;
        float zz[16];
#pragma unroll
        for (int t = 0; t < 4; ++t) {
            float4 v = *(const float4*)&lg[r][(ln << 2) + (t << 8)];
            zz[4 * t + 0] = v.x; zz[4 * t + 1] = v.y;
            zz[4 * t + 2] = v.z; zz[4 * t + 3] = v.w;
        }
        // initial stats: full support
        float s = 0.f;
#pragma unroll
        for (int e = 0; e < 16; ++e) s += zz[e];
#pragma unroll
        for (int o = 32; o > 0; o >>= 1) s += __shfl_xor(s, o);

        float tau = (s - 1.0f) * (1.0f / 1024.0f);
        int kcur = 1024;
        // Michelot: support shrinks monotonically; terminate when stable.
        for (int it = 0; it < 64; ++it) {
            float sl = 0.f; int kl = 0;
#pragma unroll
            for (int e = 0; e < 16; ++e) {
                if (zz[e] > tau) { sl += zz[e]; ++kl; }
            }
#pragma unroll
            for (int o = 32; o > 0; o >>= 1) {
                sl += __shfl_xor(sl, o);
                kl += __shfl_xor(kl, o);
            }
            if (kl == kcur) break;        // support unchanged -> tau final
            kcur = kl;
            tau = (sl - 1.0f) / (float)kl;
        }

        float* orow = out + ((size_t)n * 1024 + (size_t)(r0 + r)) * 1024;
#pragma unroll
        for (int t = 0; t < 4; ++t) {
            float4 o;
            o.x = fmaxf(zz[4 * t + 0] - tau, 0.f);
            o.y = fmaxf(zz[4 * t + 1] - tau, 0.f);
            o.z = fmaxf(zz[4 * t + 2] - tau, 0.f);
            o.w = fmaxf(zz[4 * t + 3] - tau, 0.f);
            *(float4*)&orow[(ln << 2) + (t << 8)] = o;
        }
    }
}

// ---------------------------------------------------------------------------
extern "C" void kernel_launch(void* const* d_in, const int* in_sizes, int n_in,
                              void* d_out, int out_size, void* d_ws, size_t ws_size,
                              hipStream_t stream) {
    const float* x = (const float*)d_in[0];          // [4096, 1024]
    const float* w = (const float*)d_in[1];          // [3072, 1024]
    float* out = (float*)d_out;                      // [64, 1024, 1024]
    float* kh = (float*)d_ws;                        // [64][1024][64]
    float* qh = kh + (size_t)64 * 1024 * 64;         // [64][1024][64]

    proj_kernel<<<dim3(16, 32), 256, 0, stream>>>(x, w, kh, qh);
    attn_sparsemax_kernel<<<dim3(64, 32), 256, 0, stream>>>(kh, qh, out);
}

// Round 2
// 427.331 us; speedup vs baseline: 1.7175x; 1.7175x over previous
//
#include <hip/hip_runtime.h>
#include <hip/hip_bf16.h>

// B=4, S=1024, E=1024, H=16, d=64 -> NH=64 heads. Out: [64,1024,1024] fp32.
// sparsemax(Q K^T) per head, SCALE=1.0. V chunk of the projection is dead.

typedef __attribute__((ext_vector_type(8))) short bf16x8;   // 8 bf16 = 4 VGPRs
typedef __attribute__((ext_vector_type(4))) float f32x4;

__device__ __forceinline__ ushort f2bf(float x) {           // RNE f32 -> bf16 bits
    uint u = __float_as_uint(x);
    u += 0x7FFFu + ((u >> 16) & 1u);
    return (ushort)(u >> 16);
}
__device__ __forceinline__ float bf2f(ushort h) {
    return __uint_as_float(((uint)h) << 16);
}

#define DOT4(acc, qv, kv) \
    acc = fmaf((qv).x, (kv).x, fmaf((qv).y, (kv).y, fmaf((qv).z, (kv).z, fmaf((qv).w, (kv).w, acc))))

// ---------------------------------------------------------------------------
// Kernel 1: projection  C[m][c] = sum_e x[m][e] * W[1024+c][e]
// c in [0,1024) -> K chunk, [1024,2048) -> Q chunk.
// Epilogue: split-bf16 (hi = bf16(v), lo = bf16(v - hi)) stored head-major
// [n][s][d] so MFMA fragments load as contiguous 16B per lane.
// ---------------------------------------------------------------------------
__global__ __launch_bounds__(256)
void proj_kernel(const float* __restrict__ x, const float* __restrict__ w,
                 ushort* __restrict__ khi, ushort* __restrict__ klo,
                 ushort* __restrict__ qhi, ushort* __restrict__ qlo)
{
    __shared__ __align__(16) float as_[32][132];   // [k][m]
    __shared__ __align__(16) float bs_[32][132];   // [k][c]
    const int tid = threadIdx.x;
    const int m0 = blockIdx.y * 128;
    const int c0 = blockIdx.x * 128;
    const int tx = tid & 15, ty = tid >> 4;
    const int ar = tid >> 3, ac = (tid & 7) << 2;
    const float* wb = w + (size_t)1024 * 1024;     // rows 1024.. (k then q)

    float acc[8][8];
#pragma unroll
    for (int i = 0; i < 8; ++i)
#pragma unroll
        for (int j = 0; j < 8; ++j) acc[i][j] = 0.f;

    for (int k0 = 0; k0 < 1024; k0 += 32) {
        __syncthreads();
#pragma unroll
        for (int i = 0; i < 4; ++i) {
            const int r = ar + 32 * i;
            float4 va = *(const float4*)(x  + (size_t)(m0 + r) * 1024 + k0 + ac);
            as_[ac + 0][r] = va.x; as_[ac + 1][r] = va.y;
            as_[ac + 2][r] = va.z; as_[ac + 3][r] = va.w;
            float4 vb = *(const float4*)(wb + (size_t)(c0 + r) * 1024 + k0 + ac);
            bs_[ac + 0][r] = vb.x; bs_[ac + 1][r] = vb.y;
            bs_[ac + 2][r] = vb.z; bs_[ac + 3][r] = vb.w;
        }
        __syncthreads();
#pragma unroll
        for (int kk = 0; kk < 32; ++kk) {
            float a[8], b[8];
            *(float4*)&a[0] = *(const float4*)&as_[kk][4 * ty];
            *(float4*)&a[4] = *(const float4*)&as_[kk][64 + 4 * ty];
            *(float4*)&b[0] = *(const float4*)&bs_[kk][4 * tx];
            *(float4*)&b[4] = *(const float4*)&bs_[kk][64 + 4 * tx];
#pragma unroll
            for (int i = 0; i < 8; ++i)
#pragma unroll
                for (int j = 0; j < 8; ++j)
                    acc[i][j] = fmaf(a[i], b[j], acc[i][j]);
        }
    }

#pragma unroll
    for (int i = 0; i < 8; ++i) {
        const int m = m0 + ((i < 4) ? (4 * ty + i) : (64 + 4 * ty + (i - 4)));
#pragma unroll
        for (int g = 0; g < 2; ++g) {
            const int c = c0 + g * 64 + 4 * tx;
            const int cc = c & 1023;
            const int n = ((m >> 10) << 4) + (cc >> 6);
            const size_t off = ((size_t)n << 16) + ((size_t)(m & 1023) << 6) + (cc & 63);
            ushort4 hv, lv;
            float v0 = acc[i][g * 4 + 0], v1 = acc[i][g * 4 + 1];
            float v2 = acc[i][g * 4 + 2], v3 = acc[i][g * 4 + 3];
            hv.x = f2bf(v0); lv.x = f2bf(v0 - bf2f(hv.x));
            hv.y = f2bf(v1); lv.y = f2bf(v1 - bf2f(hv.y));
            hv.z = f2bf(v2); lv.z = f2bf(v2 - bf2f(hv.z));
            hv.w = f2bf(v3); lv.w = f2bf(v3 - bf2f(hv.w));
            ushort* dh = (c < 1024) ? khi : qhi;
            ushort* dl = (c < 1024) ? klo : qlo;
            *(ushort4*)(dh + off) = hv;
            *(ushort4*)(dl + off) = lv;
        }
    }
}

// ---------------------------------------------------------------------------
// Kernel 2: fused logits MFMA-GEMM + sparsemax.
// Block = (head n, 32 q-rows), 512 threads = 8 waves.
// Wave w computes the 32x128 logit strip at cols w*128 via
// mfma_f32_16x16x32_bf16, split-bf16: hi*hi + lo*hi + hi*lo (ql*kl dropped,
// |err| <= 64 * 2^-18 * |q||k| ~ 1e-4). B fragments come straight from
// global (per-head K is 256 KB -> L2 resident). Logits -> LDS -> Michelot
// sparsemax (exact simplex projection) -> relu write.
// C/D layout (verified m89): col = lane&15, row = (lane>>4)*4 + reg.
// A/B k-mapping need not be known: both operands use the same loader, and a
// dot product is invariant under a common permutation of k.
// ---------------------------------------------------------------------------
__global__ __launch_bounds__(512)
void attn_sparsemax_kernel(const ushort* __restrict__ khi, const ushort* __restrict__ klo,
                           const ushort* __restrict__ qhi, const ushort* __restrict__ qlo,
                           float* __restrict__ out)
{
    __shared__ __align__(16) float lg[32][1024];   // 128 KB
    const int tid = threadIdx.x, wv = tid >> 6, ln = tid & 63;
    const int n = blockIdx.x, r0 = blockIdx.y * 32;
    const size_t hb = (size_t)n << 16;             // head base, elements
    const int lm = ln & 15, lk = ln >> 4;

    // A fragments: Q rows r0 + mf*16 + lm, d = kc*32 + lk*8 + j (16B/lane)
    bf16x8 qh[2][2], ql[2][2];
#pragma unroll
    for (int mf = 0; mf < 2; ++mf)
#pragma unroll
        for (int kc = 0; kc < 2; ++kc) {
            const size_t o = hb + ((size_t)(r0 + mf * 16 + lm) << 6) + kc * 32 + lk * 8;
            qh[mf][kc] = *(const bf16x8*)(qhi + o);
            ql[mf][kc] = *(const bf16x8*)(qlo + o);
        }

    f32x4 acc[2][8];
#pragma unroll
    for (int mf = 0; mf < 2; ++mf)
#pragma unroll
        for (int nf = 0; nf < 8; ++nf) acc[mf][nf] = (f32x4){0.f, 0.f, 0.f, 0.f};

    const int c0 = wv * 128;
#pragma unroll
    for (int nf = 0; nf < 8; ++nf) {
        const size_t o = hb + ((size_t)(c0 + nf * 16 + lm) << 6) + lk * 8;
        bf16x8 bh0 = *(const bf16x8*)(khi + o);
        bf16x8 bh1 = *(const bf16x8*)(khi + o + 32);
        bf16x8 bl0 = *(const bf16x8*)(klo + o);
        bf16x8 bl1 = *(const bf16x8*)(klo + o + 32);
#pragma unroll
        for (int mf = 0; mf < 2; ++mf) {
            f32x4 a = acc[mf][nf];
            a = __builtin_amdgcn_mfma_f32_16x16x32_bf16(qh[mf][0], bh0, a, 0, 0, 0);
            a = __builtin_amdgcn_mfma_f32_16x16x32_bf16(qh[mf][1], bh1, a, 0, 0, 0);
            a = __builtin_amdgcn_mfma_f32_16x16x32_bf16(ql[mf][0], bh0, a, 0, 0, 0);
            a = __builtin_amdgcn_mfma_f32_16x16x32_bf16(ql[mf][1], bh1, a, 0, 0, 0);
            a = __builtin_amdgcn_mfma_f32_16x16x32_bf16(qh[mf][0], bl0, a, 0, 0, 0);
            a = __builtin_amdgcn_mfma_f32_16x16x32_bf16(qh[mf][1], bl1, a, 0, 0, 0);
            acc[mf][nf] = a;
        }
    }

    // scatter fragments to LDS logits
#pragma unroll
    for (int mf = 0; mf < 2; ++mf)
#pragma unroll
        for (int nf = 0; nf < 8; ++nf)
#pragma unroll
            for (int rg = 0; rg < 4; ++rg)
                lg[mf * 16 + lk * 4 + rg][c0 + nf * 16 + lm] = acc[mf][nf][rg];
    __syncthreads();

    // --- sparsemax: wave wv handles rows wv*4 .. wv*4+3 ---
    for (int rr = 0; rr < 4; ++rr) {
        const int r = (wv << 2) + rr;
        float zz[16];
#pragma unroll
        for (int t = 0; t < 4; ++t) {
            float4 v = *(const float4*)&lg[r][(ln << 2) + (t << 8)];
            zz[4 * t + 0] = v.x; zz[4 * t + 1] = v.y;
            zz[4 * t + 2] = v.z; zz[4 * t + 3] = v.w;
        }
        float s = 0.f;
#pragma unroll
        for (int e = 0; e < 16; ++e) s += zz[e];
#pragma unroll
        for (int o = 32; o > 0; o >>= 1) s += __shfl_xor(s, o);

        float tau = (s - 1.0f) * (1.0f / 1024.0f);
        int kcur = 1024;
        for (int it = 0; it < 64; ++it) {
            float sl = 0.f; int kl = 0;
#pragma unroll
            for (int e = 0; e < 16; ++e) {
                if (zz[e] > tau) { sl += zz[e]; ++kl; }
            }
#pragma unroll
            for (int o = 32; o > 0; o >>= 1) {
                sl += __shfl_xor(sl, o);
                kl += __shfl_xor(kl, o);
            }
            if (kl == kcur) break;        // support stable -> tau final
            kcur = kl;
            tau = (sl - 1.0f) / (float)kl;
        }

        float* orow = out + ((size_t)n * 1024 + (size_t)(r0 + r)) * 1024;
#pragma unroll
        for (int t = 0; t < 4; ++t) {
            float4 o;
            o.x = fmaxf(zz[4 * t + 0] - tau, 0.f);
            o.y = fmaxf(zz[4 * t + 1] - tau, 0.f);
            o.z = fmaxf(zz[4 * t + 2] - tau, 0.f);
            o.w = fmaxf(zz[4 * t + 3] - tau, 0.f);
            *(float4*)&orow[(ln << 2) + (t << 8)] = o;
        }
    }
}

// ---------------------------------------------------------------------------
extern "C" void kernel_launch(void* const* d_in, const int* in_sizes, int n_in,
                              void* d_out, int out_size, void* d_ws, size_t ws_size,
                              hipStream_t stream) {
    const float* x = (const float*)d_in[0];          // [4096, 1024]
    const float* w = (const float*)d_in[1];          // [3072, 1024]
    float* out = (float*)d_out;                      // [64, 1024, 1024]
    const size_t HE = (size_t)64 * 1024 * 64;        // elems per bf16 array
    ushort* khi = (ushort*)d_ws;
    ushort* klo = khi + HE;
    ushort* qhi = klo + HE;
    ushort* qlo = qhi + HE;                          // total 32 MB of d_ws

    proj_kernel<<<dim3(16, 32), 256, 0, stream>>>(x, w, khi, klo, qhi, qlo);
    attn_sparsemax_kernel<<<dim3(64, 32), 512, 0, stream>>>(khi, klo, qhi, qlo, out);
}

// Round 3
// 244.397 us; speedup vs baseline: 3.0030x; 1.7485x over previous
//
#include <hip/hip_runtime.h>
#include <hip/hip_bf16.h>

// B=4, S=1024, E=1024, H=16, d=64 -> NH=64 heads. Out: [64,1024,1024] fp32.
// sparsemax(Q K^T) per head, SCALE=1.0. V chunk of the projection is dead.

typedef __attribute__((ext_vector_type(8))) short bf16x8;   // 8 bf16 = 4 VGPRs
typedef __attribute__((ext_vector_type(4))) float f32x4;

__device__ __forceinline__ ushort f2bf(float x) {           // RNE f32 -> bf16 bits
    uint u = __float_as_uint(x);
    u += 0x7FFFu + ((u >> 16) & 1u);
    return (ushort)(u >> 16);
}
__device__ __forceinline__ float bf2f(ushort h) {
    return __uint_as_float(((uint)h) << 16);
}

typedef const __attribute__((address_space(1))) unsigned int* gptr_t;
typedef __attribute__((address_space(3))) unsigned int* sptr_t;
__device__ __forceinline__ void gload_lds16(const void* g, void* l) {
    __builtin_amdgcn_global_load_lds((gptr_t)g, (sptr_t)l, 16, 0, 0);
}

// ---------------------------------------------------------------------------
// Kernel 0: fp32 -> split bf16 (hi = bf16(v), lo = bf16(v - hi)), elementwise.
// ---------------------------------------------------------------------------
__global__ __launch_bounds__(256)
void convert_split_kernel(const float* __restrict__ in, ushort* __restrict__ hi,
                          ushort* __restrict__ lo, int n4)
{
    int i = blockIdx.x * 256 + threadIdx.x;
    const int stride = gridDim.x * 256;
    for (; i < n4; i += stride) {
        float4 v = ((const float4*)in)[i];
        ushort4 h, l;
        h.x = f2bf(v.x); l.x = f2bf(v.x - bf2f(h.x));
        h.y = f2bf(v.y); l.y = f2bf(v.y - bf2f(h.y));
        h.z = f2bf(v.z); l.z = f2bf(v.z - bf2f(h.z));
        h.w = f2bf(v.w); l.w = f2bf(v.w - bf2f(h.w));
        ((ushort4*)hi)[i] = h;
        ((ushort4*)lo)[i] = l;
    }
}

// ---------------------------------------------------------------------------
// Kernel 1: projection GEMM via split-bf16 MFMA.
//   C[m][c] = sum_e x[m][e] * W'[c][e],  W' = rows 1024..3071 of W.
//   3 products: xh*wh + xl*wh + xh*wl  (xl*wl dropped, ~2^-18 rel).
// 128x128 tile, BK=64, 512 thr = 8 waves (2x4), global_load_lds staging with
// XOR-swizzled source so ds_read_b128 fragments are conflict-free (T21/m201):
// LDS slot (row, s) holds global 16B-chunk (row, s ^ (row&7)).
// Epilogue: split-bf16 to head-major khi/klo/qhi/qlo [n][s][d].
// C/D layout (verified on HW in round 2): m-dim = (lane>>4)*4+reg, c-dim = lane&15.
// ---------------------------------------------------------------------------
__global__ __launch_bounds__(512)
void proj_kernel(const ushort* __restrict__ xh, const ushort* __restrict__ xl,
                 const ushort* __restrict__ wh, const ushort* __restrict__ wl,
                 ushort* __restrict__ khi, ushort* __restrict__ klo,
                 ushort* __restrict__ qhi, ushort* __restrict__ qlo)
{
    __shared__ __align__(16) ushort Ah[128 * 64], Al[128 * 64];   // 16 KB each
    __shared__ __align__(16) ushort Bh[128 * 64], Bl[128 * 64];   // total 64 KB
    const int tid = threadIdx.x, w = tid >> 6, l = tid & 63;
    const int m0 = blockIdx.y * 128, c0 = blockIdx.x * 128;
    const int wr = w >> 2, wc = w & 3;          // wave -> 64m x 32c sub-tile
    const int lm = l & 15, lk = l >> 4;
    const int sslot = (l & 7) ^ (l >> 3);       // pre-swizzled source chunk

    f32x4 acc[4][2];
#pragma unroll
    for (int mf = 0; mf < 4; ++mf)
#pragma unroll
        for (int nf = 0; nf < 2; ++nf) acc[mf][nf] = (f32x4){0.f, 0.f, 0.f, 0.f};

    for (int k0 = 0; k0 < 1024; k0 += 64) {
        __syncthreads();                        // prev ds_reads done
#pragma unroll
        for (int i = 0; i < 2; ++i) {
            const int r = 16 * w + 8 * i + (l >> 3);
            const size_t ga = (size_t)(m0 + r) * 1024 + k0 + sslot * 8;
            const size_t gb = (size_t)(c0 + r) * 1024 + k0 + sslot * 8;
            const int lb = (16 * w + 8 * i) * 128;          // LDS byte base (uniform)
            gload_lds16(xh + ga, (char*)Ah + lb);
            gload_lds16(xl + ga, (char*)Al + lb);
            gload_lds16(wh + gb, (char*)Bh + lb);
            gload_lds16(wl + gb, (char*)Bl + lb);
        }
        __syncthreads();                        // vmcnt drained by barrier
#pragma unroll
        for (int kc = 0; kc < 2; ++kc) {
            bf16x8 a_h[4], a_l[4], b_h[2], b_l[2];
#pragma unroll
            for (int mf = 0; mf < 4; ++mf) {
                const int ra = wr * 64 + mf * 16 + lm;
                const int off = ra * 128 + ((kc * 4 + lk) ^ (ra & 7)) * 16;
                a_h[mf] = *(const bf16x8*)((const char*)Ah + off);
                a_l[mf] = *(const bf16x8*)((const char*)Al + off);
            }
#pragma unroll
            for (int nf = 0; nf < 2; ++nf) {
                const int rb = wc * 32 + nf * 16 + lm;
                const int off = rb * 128 + ((kc * 4 + lk) ^ (rb & 7)) * 16;
                b_h[nf] = *(const bf16x8*)((const char*)Bh + off);
                b_l[nf] = *(const bf16x8*)((const char*)Bl + off);
            }
#pragma unroll
            for (int mf = 0; mf < 4; ++mf)
#pragma unroll
                for (int nf = 0; nf < 2; ++nf) {
                    f32x4 a = acc[mf][nf];
                    a = __builtin_amdgcn_mfma_f32_16x16x32_bf16(a_h[mf], b_h[nf], a, 0, 0, 0);
                    a = __builtin_amdgcn_mfma_f32_16x16x32_bf16(a_l[mf], b_h[nf], a, 0, 0, 0);
                    a = __builtin_amdgcn_mfma_f32_16x16x32_bf16(a_h[mf], b_l[nf], a, 0, 0, 0);
                    acc[mf][nf] = a;
                }
        }
    }

    // epilogue: split-bf16, scatter to head-major K / Q buffers
#pragma unroll
    for (int mf = 0; mf < 4; ++mf)
#pragma unroll
        for (int nf = 0; nf < 2; ++nf) {
            const int c = c0 + wc * 32 + nf * 16 + lm;
            const int cc = c & 1023;
            ushort* dh = (c < 1024) ? khi : qhi;
            ushort* dl = (c < 1024) ? klo : qlo;
#pragma unroll
            for (int rg = 0; rg < 4; ++rg) {
                const int m = m0 + wr * 64 + mf * 16 + lk * 4 + rg;
                const float v = acc[mf][nf][rg];
                const ushort h = f2bf(v), lo_ = f2bf(v - bf2f(h));
                const int nhd = ((m >> 10) << 4) + (cc >> 6);
                const size_t off = ((size_t)nhd << 16) + ((size_t)(m & 1023) << 6) + (cc & 63);
                dh[off] = h;
                dl[off] = lo_;
            }
        }
}

// ---------------------------------------------------------------------------
// Kernel 2: fused logits MFMA-GEMM + sparsemax.
// Block = (head n, 16 q-rows), 512 threads = 8 waves; 2 blocks/CU (64.3 KB LDS).
// Wave w computes the 16x128 logit strip at cols w*128 (split-bf16, 3 MFMA
// products, B frags straight from L2-resident global K), scatters to LDS
// (row pad 1028 -> 2-way store aliasing = free), then Michelot sparsemax
// (exact simplex projection), 2 rows/wave, fused relu write.
// ---------------------------------------------------------------------------
__global__ __launch_bounds__(512)
void attn_sparsemax_kernel(const ushort* __restrict__ khi, const ushort* __restrict__ klo,
                           const ushort* __restrict__ qhi, const ushort* __restrict__ qlo,
                           float* __restrict__ out)
{
    __shared__ __align__(16) float lg[16][1028];   // 65792 B
    const int tid = threadIdx.x, wv = tid >> 6, ln = tid & 63;
    const int n = blockIdx.x, r0 = blockIdx.y * 16;
    const size_t hb = (size_t)n << 16;             // head base, elements
    const int lm = ln & 15, lk = ln >> 4;

    // A fragments: Q rows r0 + lm, d = kc*32 + lk*8 + j (16B/lane)
    bf16x8 qh[2], ql[2];
#pragma unroll
    for (int kc = 0; kc < 2; ++kc) {
        const size_t o = hb + ((size_t)(r0 + lm) << 6) + kc * 32 + lk * 8;
        qh[kc] = *(const bf16x8*)(qhi + o);
        ql[kc] = *(const bf16x8*)(qlo + o);
    }

    f32x4 acc[8];
#pragma unroll
    for (int nf = 0; nf < 8; ++nf) acc[nf] = (f32x4){0.f, 0.f, 0.f, 0.f};

    const int c0 = wv * 128;
#pragma unroll
    for (int nf = 0; nf < 8; ++nf) {
        const size_t o = hb + ((size_t)(c0 + nf * 16 + lm) << 6) + lk * 8;
        bf16x8 bh0 = *(const bf16x8*)(khi + o);
        bf16x8 bh1 = *(const bf16x8*)(khi + o + 32);
        bf16x8 bl0 = *(const bf16x8*)(klo + o);
        bf16x8 bl1 = *(const bf16x8*)(klo + o + 32);
        f32x4 a = acc[nf];
        a = __builtin_amdgcn_mfma_f32_16x16x32_bf16(qh[0], bh0, a, 0, 0, 0);
        a = __builtin_amdgcn_mfma_f32_16x16x32_bf16(qh[1], bh1, a, 0, 0, 0);
        a = __builtin_amdgcn_mfma_f32_16x16x32_bf16(ql[0], bh0, a, 0, 0, 0);
        a = __builtin_amdgcn_mfma_f32_16x16x32_bf16(ql[1], bh1, a, 0, 0, 0);
        a = __builtin_amdgcn_mfma_f32_16x16x32_bf16(qh[0], bl0, a, 0, 0, 0);
        a = __builtin_amdgcn_mfma_f32_16x16x32_bf16(qh[1], bl1, a, 0, 0, 0);
        acc[nf] = a;
    }

    // scatter fragments to LDS logits (rows lk*4+rg, col lm-strip)
#pragma unroll
    for (int nf = 0; nf < 8; ++nf)
#pragma unroll
        for (int rg = 0; rg < 4; ++rg)
            lg[lk * 4 + rg][c0 + nf * 16 + lm] = acc[nf][rg];
    __syncthreads();

    // --- sparsemax: wave wv handles rows wv*2, wv*2+1 ---
    for (int rr = 0; rr < 2; ++rr) {
        const int r = (wv << 1) + rr;
        float zz[16];
#pragma unroll
        for (int t = 0; t < 4; ++t) {
            float4 v = *(const float4*)&lg[r][(ln << 2) + (t << 8)];
            zz[4 * t + 0] = v.x; zz[4 * t + 1] = v.y;
            zz[4 * t + 2] = v.z; zz[4 * t + 3] = v.w;
        }
        float s = 0.f;
#pragma unroll
        for (int e = 0; e < 16; ++e) s += zz[e];
#pragma unroll
        for (int o = 32; o > 0; o >>= 1) s += __shfl_xor(s, o);

        float tau = (s - 1.0f) * (1.0f / 1024.0f);
        int kcur = 1024;
        for (int it = 0; it < 64; ++it) {
            float sl = 0.f; int kl = 0;
#pragma unroll
            for (int e = 0; e < 16; ++e) {
                if (zz[e] > tau) { sl += zz[e]; ++kl; }
            }
#pragma unroll
            for (int o = 32; o > 0; o >>= 1) {
                sl += __shfl_xor(sl, o);
                kl += __shfl_xor(kl, o);
            }
            if (kl == kcur) break;        // support stable -> tau final
            kcur = kl;
            tau = (sl - 1.0f) / (float)kl;
        }

        float* orow = out + ((size_t)n * 1024 + (size_t)(r0 + r)) * 1024;
#pragma unroll
        for (int t = 0; t < 4; ++t) {
            float4 o;
            o.x = fmaxf(zz[4 * t + 0] - tau, 0.f);
            o.y = fmaxf(zz[4 * t + 1] - tau, 0.f);
            o.z = fmaxf(zz[4 * t + 2] - tau, 0.f);
            o.w = fmaxf(zz[4 * t + 3] - tau, 0.f);
            *(float4*)&orow[(ln << 2) + (t << 8)] = o;
        }
    }
}

// ---------------------------------------------------------------------------
extern "C" void kernel_launch(void* const* d_in, const int* in_sizes, int n_in,
                              void* d_out, int out_size, void* d_ws, size_t ws_size,
                              hipStream_t stream) {
    const float* x = (const float*)d_in[0];          // [4096, 1024]
    const float* w = (const float*)d_in[1];          // [3072, 1024]
    float* out = (float*)d_out;                      // [64, 1024, 1024]

    const size_t HE = (size_t)64 * 1024 * 64;        // 4.19M elems per head buf
    const size_t XE = (size_t)4096 * 1024;           // x elems
    const size_t WE = (size_t)2048 * 1024;           // W' elems (rows 1024..3071)
    ushort* khi = (ushort*)d_ws;
    ushort* klo = khi + HE;
    ushort* qhi = klo + HE;
    ushort* qlo = qhi + HE;
    ushort* xh  = qlo + HE;
    ushort* xl  = xh + XE;
    ushort* wh  = xl + XE;
    ushort* wl  = wh + WE;                           // total ~58.7 MB of d_ws

    convert_split_kernel<<<2048, 256, 0, stream>>>(x, xh, xl, (int)(XE / 4));
    convert_split_kernel<<<2048, 256, 0, stream>>>(w + (size_t)1024 * 1024, wh, wl, (int)(WE / 4));
    proj_kernel<<<dim3(16, 32), 512, 0, stream>>>(xh, xl, wh, wl, khi, klo, qhi, qlo);
    attn_sparsemax_kernel<<<dim3(64, 64), 512, 0, stream>>>(khi, klo, qhi, qlo, out);
}

// Round 4
// 215.843 us; speedup vs baseline: 3.4003x; 1.1323x over previous
//
#include <hip/hip_runtime.h>
#include <hip/hip_bf16.h>

// B=4, S=1024, E=1024, H=16, d=64 -> NH=64 heads. Out: [64,1024,1024] fp32.
// sparsemax(Q K^T) per head, SCALE=1.0. V chunk of the projection is dead.

typedef __attribute__((ext_vector_type(8))) short bf16x8;   // 8 bf16 = 4 VGPRs
typedef __attribute__((ext_vector_type(4))) float f32x4;

__device__ __forceinline__ ushort f2bf(float x) {           // RNE f32 -> bf16 bits
    uint u = __float_as_uint(x);
    u += 0x7FFFu + ((u >> 16) & 1u);
    return (ushort)(u >> 16);
}
__device__ __forceinline__ float bf2f(ushort h) {
    return __uint_as_float(((uint)h) << 16);
}

typedef const __attribute__((address_space(1))) unsigned int* gptr_t;
typedef __attribute__((address_space(3))) unsigned int* sptr_t;
__device__ __forceinline__ void gload_lds16(const void* g, void* l) {
    __builtin_amdgcn_global_load_lds((gptr_t)g, (sptr_t)l, 16, 0, 0);
}

// ---------------------------------------------------------------------------
// Kernel 0: fp32 -> split bf16 (hi = bf16(v), lo = bf16(v - hi)), elementwise.
// ---------------------------------------------------------------------------
__global__ __launch_bounds__(256)
void convert_split_kernel(const float* __restrict__ in, ushort* __restrict__ hi,
                          ushort* __restrict__ lo, int n4)
{
    int i = blockIdx.x * 256 + threadIdx.x;
    const int stride = gridDim.x * 256;
    for (; i < n4; i += stride) {
        float4 v = ((const float4*)in)[i];
        ushort4 h, l;
        h.x = f2bf(v.x); l.x = f2bf(v.x - bf2f(h.x));
        h.y = f2bf(v.y); l.y = f2bf(v.y - bf2f(h.y));
        h.z = f2bf(v.z); l.z = f2bf(v.z - bf2f(h.z));
        h.w = f2bf(v.w); l.w = f2bf(v.w - bf2f(h.w));
        ((ushort4*)hi)[i] = h;
        ((ushort4*)lo)[i] = l;
    }
}

// ---------------------------------------------------------------------------
// Kernel 1: projection GEMM via split-bf16 MFMA (unchanged from round 3).
// ---------------------------------------------------------------------------
__global__ __launch_bounds__(512)
void proj_kernel(const ushort* __restrict__ xh, const ushort* __restrict__ xl,
                 const ushort* __restrict__ wh, const ushort* __restrict__ wl,
                 ushort* __restrict__ khi, ushort* __restrict__ klo,
                 ushort* __restrict__ qhi, ushort* __restrict__ qlo)
{
    __shared__ __align__(16) ushort Ah[128 * 64], Al[128 * 64];   // 16 KB each
    __shared__ __align__(16) ushort Bh[128 * 64], Bl[128 * 64];   // total 64 KB
    const int tid = threadIdx.x, w = tid >> 6, l = tid & 63;
    const int m0 = blockIdx.y * 128, c0 = blockIdx.x * 128;
    const int wr = w >> 2, wc = w & 3;          // wave -> 64m x 32c sub-tile
    const int lm = l & 15, lk = l >> 4;
    const int sslot = (l & 7) ^ (l >> 3);       // pre-swizzled source chunk

    f32x4 acc[4][2];
#pragma unroll
    for (int mf = 0; mf < 4; ++mf)
#pragma unroll
        for (int nf = 0; nf < 2; ++nf) acc[mf][nf] = (f32x4){0.f, 0.f, 0.f, 0.f};

    for (int k0 = 0; k0 < 1024; k0 += 64) {
        __syncthreads();                        // prev ds_reads done
#pragma unroll
        for (int i = 0; i < 2; ++i) {
            const int r = 16 * w + 8 * i + (l >> 3);
            const size_t ga = (size_t)(m0 + r) * 1024 + k0 + sslot * 8;
            const size_t gb = (size_t)(c0 + r) * 1024 + k0 + sslot * 8;
            const int lb = (16 * w + 8 * i) * 128;          // LDS byte base (uniform)
            gload_lds16(xh + ga, (char*)Ah + lb);
            gload_lds16(xl + ga, (char*)Al + lb);
            gload_lds16(wh + gb, (char*)Bh + lb);
            gload_lds16(wl + gb, (char*)Bl + lb);
        }
        __syncthreads();                        // vmcnt drained by barrier
#pragma unroll
        for (int kc = 0; kc < 2; ++kc) {
            bf16x8 a_h[4], a_l[4], b_h[2], b_l[2];
#pragma unroll
            for (int mf = 0; mf < 4; ++mf) {
                const int ra = wr * 64 + mf * 16 + lm;
                const int off = ra * 128 + ((kc * 4 + lk) ^ (ra & 7)) * 16;
                a_h[mf] = *(const bf16x8*)((const char*)Ah + off);
                a_l[mf] = *(const bf16x8*)((const char*)Al + off);
            }
#pragma unroll
            for (int nf = 0; nf < 2; ++nf) {
                const int rb = wc * 32 + nf * 16 + lm;
                const int off = rb * 128 + ((kc * 4 + lk) ^ (rb & 7)) * 16;
                b_h[nf] = *(const bf16x8*)((const char*)Bh + off);
                b_l[nf] = *(const bf16x8*)((const char*)Bl + off);
            }
#pragma unroll
            for (int mf = 0; mf < 4; ++mf)
#pragma unroll
                for (int nf = 0; nf < 2; ++nf) {
                    f32x4 a = acc[mf][nf];
                    a = __builtin_amdgcn_mfma_f32_16x16x32_bf16(a_h[mf], b_h[nf], a, 0, 0, 0);
                    a = __builtin_amdgcn_mfma_f32_16x16x32_bf16(a_l[mf], b_h[nf], a, 0, 0, 0);
                    a = __builtin_amdgcn_mfma_f32_16x16x32_bf16(a_h[mf], b_l[nf], a, 0, 0, 0);
                    acc[mf][nf] = a;
                }
        }
    }

    // epilogue: split-bf16, scatter to head-major K / Q buffers
#pragma unroll
    for (int mf = 0; mf < 4; ++mf)
#pragma unroll
        for (int nf = 0; nf < 2; ++nf) {
            const int c = c0 + wc * 32 + nf * 16 + lm;
            const int cc = c & 1023;
            ushort* dh = (c < 1024) ? khi : qhi;
            ushort* dl = (c < 1024) ? klo : qlo;
#pragma unroll
            for (int rg = 0; rg < 4; ++rg) {
                const int m = m0 + wr * 64 + mf * 16 + lk * 4 + rg;
                const float v = acc[mf][nf][rg];
                const ushort h = f2bf(v), lo_ = f2bf(v - bf2f(h));
                const int nhd = ((m >> 10) << 4) + (cc >> 6);
                const size_t off = ((size_t)nhd << 16) + ((size_t)(m & 1023) << 6) + (cc & 63);
                dh[off] = h;
                dl[off] = lo_;
            }
        }
}

// ---------------------------------------------------------------------------
// Kernel 2: fused logits MFMA-GEMM + sparsemax.
// Block = (head n, 16 q-rows), 512 threads = 8 waves; 2 blocks/CU (64.3 KB LDS).
// Sparsemax: Michelot with tau0 = rowmax - 1 (valid: p_max <= 1 => tau* >=
// max-1, and max in S0 gives tau1 > max-1, monotone up to tau* -> converges
// in ~2-3 scans instead of ~12 from full support). The wave's 2 rows are
// processed jointly so the dependent shuffle-reduce chains overlap.
// ---------------------------------------------------------------------------
__global__ __launch_bounds__(512)
void attn_sparsemax_kernel(const ushort* __restrict__ khi, const ushort* __restrict__ klo,
                           const ushort* __restrict__ qhi, const ushort* __restrict__ qlo,
                           float* __restrict__ out)
{
    __shared__ __align__(16) float lg[16][1028];   // 65792 B
    const int tid = threadIdx.x, wv = tid >> 6, ln = tid & 63;
    const int n = blockIdx.x, r0 = blockIdx.y * 16;
    const size_t hb = (size_t)n << 16;             // head base, elements
    const int lm = ln & 15, lk = ln >> 4;

    // A fragments: Q rows r0 + lm, d = kc*32 + lk*8 + j (16B/lane)
    bf16x8 qh[2], ql[2];
#pragma unroll
    for (int kc = 0; kc < 2; ++kc) {
        const size_t o = hb + ((size_t)(r0 + lm) << 6) + kc * 32 + lk * 8;
        qh[kc] = *(const bf16x8*)(qhi + o);
        ql[kc] = *(const bf16x8*)(qlo + o);
    }

    f32x4 acc[8];
#pragma unroll
    for (int nf = 0; nf < 8; ++nf) acc[nf] = (f32x4){0.f, 0.f, 0.f, 0.f};

    const int c0 = wv * 128;
#pragma unroll
    for (int nf = 0; nf < 8; ++nf) {
        const size_t o = hb + ((size_t)(c0 + nf * 16 + lm) << 6) + lk * 8;
        bf16x8 bh0 = *(const bf16x8*)(khi + o);
        bf16x8 bh1 = *(const bf16x8*)(khi + o + 32);
        bf16x8 bl0 = *(const bf16x8*)(klo + o);
        bf16x8 bl1 = *(const bf16x8*)(klo + o + 32);
        f32x4 a = acc[nf];
        a = __builtin_amdgcn_mfma_f32_16x16x32_bf16(qh[0], bh0, a, 0, 0, 0);
        a = __builtin_amdgcn_mfma_f32_16x16x32_bf16(qh[1], bh1, a, 0, 0, 0);
        a = __builtin_amdgcn_mfma_f32_16x16x32_bf16(ql[0], bh0, a, 0, 0, 0);
        a = __builtin_amdgcn_mfma_f32_16x16x32_bf16(ql[1], bh1, a, 0, 0, 0);
        a = __builtin_amdgcn_mfma_f32_16x16x32_bf16(qh[0], bl0, a, 0, 0, 0);
        a = __builtin_amdgcn_mfma_f32_16x16x32_bf16(qh[1], bl1, a, 0, 0, 0);
        acc[nf] = a;
    }

    // scatter fragments to LDS logits (rows lk*4+rg, col lm-strip)
#pragma unroll
    for (int nf = 0; nf < 8; ++nf)
#pragma unroll
        for (int rg = 0; rg < 4; ++rg)
            lg[lk * 4 + rg][c0 + nf * 16 + lm] = acc[nf][rg];
    __syncthreads();

    // --- sparsemax: wave wv handles rows 2*wv and 2*wv+1, jointly ---
    float zz[2][16];
#pragma unroll
    for (int rw = 0; rw < 2; ++rw) {
        const int r = (wv << 1) + rw;
#pragma unroll
        for (int t = 0; t < 4; ++t) {
            float4 v = *(const float4*)&lg[r][(ln << 2) + (t << 8)];
            zz[rw][4 * t + 0] = v.x; zz[rw][4 * t + 1] = v.y;
            zz[rw][4 * t + 2] = v.z; zz[rw][4 * t + 3] = v.w;
        }
    }

    // row maxes (paired reduce chains)
    float mx[2];
#pragma unroll
    for (int rw = 0; rw < 2; ++rw) {
        float m = zz[rw][0];
#pragma unroll
        for (int e = 1; e < 16; ++e) m = fmaxf(m, zz[rw][e]);
        mx[rw] = m;
    }
#pragma unroll
    for (int o = 32; o > 0; o >>= 1) {
#pragma unroll
        for (int rw = 0; rw < 2; ++rw)
            mx[rw] = fmaxf(mx[rw], __shfl_xor(mx[rw], o));
    }

    float tau[2] = {mx[0] - 1.0f, mx[1] - 1.0f};
    int kcur[2] = {0, 0};
    for (int it = 0; it < 64; ++it) {
        float sl[2] = {0.f, 0.f};
        int   kl[2] = {0, 0};
#pragma unroll
        for (int rw = 0; rw < 2; ++rw)
#pragma unroll
            for (int e = 0; e < 16; ++e) {
                if (zz[rw][e] > tau[rw]) { sl[rw] += zz[rw][e]; ++kl[rw]; }
            }
#pragma unroll
        for (int o = 32; o > 0; o >>= 1) {
#pragma unroll
            for (int rw = 0; rw < 2; ++rw) {
                sl[rw] += __shfl_xor(sl[rw], o);
                kl[rw] += __shfl_xor(kl[rw], o);
            }
        }
        const bool done0 = (kl[0] == kcur[0]), done1 = (kl[1] == kcur[1]);
        if (done0 && done1) break;     // both supports stable -> taus final
#pragma unroll
        for (int rw = 0; rw < 2; ++rw) {
            kcur[rw] = kl[rw];
            tau[rw] = (sl[rw] - 1.0f) / (float)kl[rw];   // no-op if row converged
        }
    }

#pragma unroll
    for (int rw = 0; rw < 2; ++rw) {
        const int r = (wv << 1) + rw;
        float* orow = out + ((size_t)n * 1024 + (size_t)(r0 + r)) * 1024;
#pragma unroll
        for (int t = 0; t < 4; ++t) {
            float4 o;
            o.x = fmaxf(zz[rw][4 * t + 0] - tau[rw], 0.f);
            o.y = fmaxf(zz[rw][4 * t + 1] - tau[rw], 0.f);
            o.z = fmaxf(zz[rw][4 * t + 2] - tau[rw], 0.f);
            o.w = fmaxf(zz[rw][4 * t + 3] - tau[rw], 0.f);
            *(float4*)&orow[(ln << 2) + (t << 8)] = o;
        }
    }
}

// ---------------------------------------------------------------------------
extern "C" void kernel_launch(void* const* d_in, const int* in_sizes, int n_in,
                              void* d_out, int out_size, void* d_ws, size_t ws_size,
                              hipStream_t stream) {
    const float* x = (const float*)d_in[0];          // [4096, 1024]
    const float* w = (const float*)d_in[1];          // [3072, 1024]
    float* out = (float*)d_out;                      // [64, 1024, 1024]

    const size_t HE = (size_t)64 * 1024 * 64;        // 4.19M elems per head buf
    const size_t XE = (size_t)4096 * 1024;           // x elems
    const size_t WE = (size_t)2048 * 1024;           // W' elems (rows 1024..3071)
    ushort* khi = (ushort*)d_ws;
    ushort* klo = khi + HE;
    ushort* qhi = klo + HE;
    ushort* qlo = qhi + HE;
    ushort* xh  = qlo + HE;
    ushort* xl  = xh + XE;
    ushort* wh  = xl + XE;
    ushort* wl  = wh + WE;                           // total ~58.7 MB of d_ws

    convert_split_kernel<<<2048, 256, 0, stream>>>(x, xh, xl, (int)(XE / 4));
    convert_split_kernel<<<2048, 256, 0, stream>>>(w + (size_t)1024 * 1024, wh, wl, (int)(WE / 4));
    proj_kernel<<<dim3(16, 32), 512, 0, stream>>>(xh, xl, wh, wl, khi, klo, qhi, qlo);
    attn_sparsemax_kernel<<<dim3(64, 64), 512, 0, stream>>>(khi, klo, qhi, qlo, out);
}

// Round 5
// 206.012 us; speedup vs baseline: 3.5625x; 1.0477x over previous
//
#include <hip/hip_runtime.h>
#include <hip/hip_bf16.h>

// B=4, S=1024, E=1024, H=16, d=64 -> NH=64 heads. Out: [64,1024,1024] fp32.
// sparsemax(Q K^T) per head, SCALE=1.0. V chunk of the projection is dead.

typedef __attribute__((ext_vector_type(8))) short bf16x8;   // 8 bf16 = 4 VGPRs
typedef __attribute__((ext_vector_type(4))) float f32x4;

__device__ __forceinline__ ushort f2bf(float x) {           // RNE f32 -> bf16 bits
    uint u = __float_as_uint(x);
    u += 0x7FFFu + ((u >> 16) & 1u);
    return (ushort)(u >> 16);
}
__device__ __forceinline__ float bf2f(ushort h) {
    return __uint_as_float(((uint)h) << 16);
}

typedef const __attribute__((address_space(1))) unsigned int* gptr_t;
typedef __attribute__((address_space(3))) unsigned int* sptr_t;
__device__ __forceinline__ void gload_lds16(const void* g, void* l) {
    __builtin_amdgcn_global_load_lds((gptr_t)g, (sptr_t)l, 16, 0, 0);
}

// ---------------------------------------------------------------------------
// Kernel 0: fp32 -> split bf16 (hi = bf16(v), lo = bf16(v - hi)), elementwise.
// ---------------------------------------------------------------------------
__global__ __launch_bounds__(256)
void convert_split_kernel(const float* __restrict__ in, ushort* __restrict__ hi,
                          ushort* __restrict__ lo, int n4)
{
    int i = blockIdx.x * 256 + threadIdx.x;
    const int stride = gridDim.x * 256;
    for (; i < n4; i += stride) {
        float4 v = ((const float4*)in)[i];
        ushort4 h, l;
        h.x = f2bf(v.x); l.x = f2bf(v.x - bf2f(h.x));
        h.y = f2bf(v.y); l.y = f2bf(v.y - bf2f(h.y));
        h.z = f2bf(v.z); l.z = f2bf(v.z - bf2f(h.z));
        h.w = f2bf(v.w); l.w = f2bf(v.w - bf2f(h.w));
        ((ushort4*)hi)[i] = h;
        ((ushort4*)lo)[i] = l;
    }
}

// ---------------------------------------------------------------------------
// Kernel 1: projection GEMM via split-bf16 MFMA (unchanged from round 3).
// ---------------------------------------------------------------------------
__global__ __launch_bounds__(512)
void proj_kernel(const ushort* __restrict__ xh, const ushort* __restrict__ xl,
                 const ushort* __restrict__ wh, const ushort* __restrict__ wl,
                 ushort* __restrict__ khi, ushort* __restrict__ klo,
                 ushort* __restrict__ qhi, ushort* __restrict__ qlo)
{
    __shared__ __align__(16) ushort Ah[128 * 64], Al[128 * 64];   // 16 KB each
    __shared__ __align__(16) ushort Bh[128 * 64], Bl[128 * 64];   // total 64 KB
    const int tid = threadIdx.x, w = tid >> 6, l = tid & 63;
    const int m0 = blockIdx.y * 128, c0 = blockIdx.x * 128;
    const int wr = w >> 2, wc = w & 3;          // wave -> 64m x 32c sub-tile
    const int lm = l & 15, lk = l >> 4;
    const int sslot = (l & 7) ^ (l >> 3);       // pre-swizzled source chunk

    f32x4 acc[4][2];
#pragma unroll
    for (int mf = 0; mf < 4; ++mf)
#pragma unroll
        for (int nf = 0; nf < 2; ++nf) acc[mf][nf] = (f32x4){0.f, 0.f, 0.f, 0.f};

    for (int k0 = 0; k0 < 1024; k0 += 64) {
        __syncthreads();                        // prev ds_reads done
#pragma unroll
        for (int i = 0; i < 2; ++i) {
            const int r = 16 * w + 8 * i + (l >> 3);
            const size_t ga = (size_t)(m0 + r) * 1024 + k0 + sslot * 8;
            const size_t gb = (size_t)(c0 + r) * 1024 + k0 + sslot * 8;
            const int lb = (16 * w + 8 * i) * 128;          // LDS byte base (uniform)
            gload_lds16(xh + ga, (char*)Ah + lb);
            gload_lds16(xl + ga, (char*)Al + lb);
            gload_lds16(wh + gb, (char*)Bh + lb);
            gload_lds16(wl + gb, (char*)Bl + lb);
        }
        __syncthreads();                        // vmcnt drained by barrier
#pragma unroll
        for (int kc = 0; kc < 2; ++kc) {
            bf16x8 a_h[4], a_l[4], b_h[2], b_l[2];
#pragma unroll
            for (int mf = 0; mf < 4; ++mf) {
                const int ra = wr * 64 + mf * 16 + lm;
                const int off = ra * 128 + ((kc * 4 + lk) ^ (ra & 7)) * 16;
                a_h[mf] = *(const bf16x8*)((const char*)Ah + off);
                a_l[mf] = *(const bf16x8*)((const char*)Al + off);
            }
#pragma unroll
            for (int nf = 0; nf < 2; ++nf) {
                const int rb = wc * 32 + nf * 16 + lm;
                const int off = rb * 128 + ((kc * 4 + lk) ^ (rb & 7)) * 16;
                b_h[nf] = *(const bf16x8*)((const char*)Bh + off);
                b_l[nf] = *(const bf16x8*)((const char*)Bl + off);
            }
#pragma unroll
            for (int mf = 0; mf < 4; ++mf)
#pragma unroll
                for (int nf = 0; nf < 2; ++nf) {
                    f32x4 a = acc[mf][nf];
                    a = __builtin_amdgcn_mfma_f32_16x16x32_bf16(a_h[mf], b_h[nf], a, 0, 0, 0);
                    a = __builtin_amdgcn_mfma_f32_16x16x32_bf16(a_l[mf], b_h[nf], a, 0, 0, 0);
                    a = __builtin_amdgcn_mfma_f32_16x16x32_bf16(a_h[mf], b_l[nf], a, 0, 0, 0);
                    acc[mf][nf] = a;
                }
        }
    }

    // epilogue: split-bf16, scatter to head-major K / Q buffers
#pragma unroll
    for (int mf = 0; mf < 4; ++mf)
#pragma unroll
        for (int nf = 0; nf < 2; ++nf) {
            const int c = c0 + wc * 32 + nf * 16 + lm;
            const int cc = c & 1023;
            ushort* dh = (c < 1024) ? khi : qhi;
            ushort* dl = (c < 1024) ? klo : qlo;
#pragma unroll
            for (int rg = 0; rg < 4; ++rg) {
                const int m = m0 + wr * 64 + mf * 16 + lk * 4 + rg;
                const float v = acc[mf][nf][rg];
                const ushort h = f2bf(v), lo_ = f2bf(v - bf2f(h));
                const int nhd = ((m >> 10) << 4) + (cc >> 6);
                const size_t off = ((size_t)nhd << 16) + ((size_t)(m & 1023) << 6) + (cc & 63);
                dh[off] = h;
                dl[off] = lo_;
            }
        }
}

// ---------------------------------------------------------------------------
// Kernel 2: fused logits MFMA-GEMM + sparsemax.
// Block = (head n, 16 q-rows), 512 threads = 8 waves; 2 blocks/CU (64.3 KB LDS).
// Round-5 changes:
//  - XCD-chunked swizzle: vb=(bid%8)*512+bid/8, head=vb/64 -> each XCD works
//    one head at a time; its resident blocks share one 512 KB K set (L2-hit).
//  - Non-temporal output stores: the 262 MB write-once stream no longer
//    evicts K/Q from L2.
//  - Depth-1 manual prefetch of K fragments + 32-bit offset addressing:
//    loads for nf+1 issue before nf's MFMA chain.
// Sparsemax: Michelot with tau0 = rowmax-1, 2 rows/wave jointly (round 4).
// ---------------------------------------------------------------------------
__global__ __launch_bounds__(512)
void attn_sparsemax_kernel(const ushort* __restrict__ khi, const ushort* __restrict__ klo,
                           const ushort* __restrict__ qhi, const ushort* __restrict__ qlo,
                           float* __restrict__ out)
{
    __shared__ __align__(16) float lg[16][1028];   // 65792 B
    const int tid = threadIdx.x, wv = tid >> 6, ln = tid & 63;
    const int bid = blockIdx.y * gridDim.x + blockIdx.x;     // linear dispatch id
    const int vb  = (bid & 7) * 512 + (bid >> 3);            // XCD-chunked remap
    const int n   = vb >> 6;                                 // head 0..63
    const int r0  = (vb & 63) << 4;                          // q-row base
    const size_t hb = (size_t)n << 16;                       // head base, elems
    const int lm = ln & 15, lk = ln >> 4;

    // A fragments: Q rows r0 + lm, d = kc*32 + lk*8 + j (16B/lane)
    bf16x8 qh[2], ql[2];
#pragma unroll
    for (int kc = 0; kc < 2; ++kc) {
        const size_t o = hb + ((size_t)(r0 + lm) << 6) + kc * 32 + lk * 8;
        qh[kc] = *(const bf16x8*)(qhi + o);
        ql[kc] = *(const bf16x8*)(qlo + o);
    }

    f32x4 acc[8];
#pragma unroll
    for (int nf = 0; nf < 8; ++nf) acc[nf] = (f32x4){0.f, 0.f, 0.f, 0.f};

    const int c0 = wv * 128;
    // hoisted base: fragment nf lives at Kh + nf*1024 (+32 second d-half)
    const ushort* Kh = khi + hb + (((size_t)(c0 + lm)) << 6) + lk * 8;
    const ushort* Kl = klo + hb + (((size_t)(c0 + lm)) << 6) + lk * 8;

    bf16x8 ch0 = *(const bf16x8*)(Kh);
    bf16x8 ch1 = *(const bf16x8*)(Kh + 32);
    bf16x8 cl0 = *(const bf16x8*)(Kl);
    bf16x8 cl1 = *(const bf16x8*)(Kl + 32);
#pragma unroll
    for (int nf = 0; nf < 8; ++nf) {
        bf16x8 nh0, nh1, nl0, nl1;
        if (nf < 7) {                           // prefetch next fragment set
            const ushort* ph = Kh + ((nf + 1) << 10);
            const ushort* pl = Kl + ((nf + 1) << 10);
            nh0 = *(const bf16x8*)(ph);
            nh1 = *(const bf16x8*)(ph + 32);
            nl0 = *(const bf16x8*)(pl);
            nl1 = *(const bf16x8*)(pl + 32);
        }
        f32x4 a = acc[nf];
        a = __builtin_amdgcn_mfma_f32_16x16x32_bf16(qh[0], ch0, a, 0, 0, 0);
        a = __builtin_amdgcn_mfma_f32_16x16x32_bf16(qh[1], ch1, a, 0, 0, 0);
        a = __builtin_amdgcn_mfma_f32_16x16x32_bf16(ql[0], ch0, a, 0, 0, 0);
        a = __builtin_amdgcn_mfma_f32_16x16x32_bf16(ql[1], ch1, a, 0, 0, 0);
        a = __builtin_amdgcn_mfma_f32_16x16x32_bf16(qh[0], cl0, a, 0, 0, 0);
        a = __builtin_amdgcn_mfma_f32_16x16x32_bf16(qh[1], cl1, a, 0, 0, 0);
        acc[nf] = a;
        if (nf < 7) { ch0 = nh0; ch1 = nh1; cl0 = nl0; cl1 = nl1; }
    }

    // scatter fragments to LDS logits (rows lk*4+rg, col lm-strip)
#pragma unroll
    for (int nf = 0; nf < 8; ++nf)
#pragma unroll
        for (int rg = 0; rg < 4; ++rg)
            lg[lk * 4 + rg][c0 + nf * 16 + lm] = acc[nf][rg];
    __syncthreads();

    // --- sparsemax: wave wv handles rows 2*wv and 2*wv+1, jointly ---
    float zz[2][16];
#pragma unroll
    for (int rw = 0; rw < 2; ++rw) {
        const int r = (wv << 1) + rw;
#pragma unroll
        for (int t = 0; t < 4; ++t) {
            float4 v = *(const float4*)&lg[r][(ln << 2) + (t << 8)];
            zz[rw][4 * t + 0] = v.x; zz[rw][4 * t + 1] = v.y;
            zz[rw][4 * t + 2] = v.z; zz[rw][4 * t + 3] = v.w;
        }
    }

    // row maxes (paired reduce chains)
    float mx[2];
#pragma unroll
    for (int rw = 0; rw < 2; ++rw) {
        float m = zz[rw][0];
#pragma unroll
        for (int e = 1; e < 16; ++e) m = fmaxf(m, zz[rw][e]);
        mx[rw] = m;
    }
#pragma unroll
    for (int o = 32; o > 0; o >>= 1) {
#pragma unroll
        for (int rw = 0; rw < 2; ++rw)
            mx[rw] = fmaxf(mx[rw], __shfl_xor(mx[rw], o));
    }

    float tau[2] = {mx[0] - 1.0f, mx[1] - 1.0f};
    int kcur[2] = {0, 0};
    for (int it = 0; it < 64; ++it) {
        float sl[2] = {0.f, 0.f};
        int   kl[2] = {0, 0};
#pragma unroll
        for (int rw = 0; rw < 2; ++rw)
#pragma unroll
            for (int e = 0; e < 16; ++e) {
                if (zz[rw][e] > tau[rw]) { sl[rw] += zz[rw][e]; ++kl[rw]; }
            }
#pragma unroll
        for (int o = 32; o > 0; o >>= 1) {
#pragma unroll
            for (int rw = 0; rw < 2; ++rw) {
                sl[rw] += __shfl_xor(sl[rw], o);
                kl[rw] += __shfl_xor(kl[rw], o);
            }
        }
        const bool done0 = (kl[0] == kcur[0]), done1 = (kl[1] == kcur[1]);
        if (done0 && done1) break;     // both supports stable -> taus final
#pragma unroll
        for (int rw = 0; rw < 2; ++rw) {
            kcur[rw] = kl[rw];
            tau[rw] = (sl[rw] - 1.0f) / (float)kl[rw];   // no-op if row converged
        }
    }

#pragma unroll
    for (int rw = 0; rw < 2; ++rw) {
        const int r = (wv << 1) + rw;
        float* orow = out + ((size_t)n * 1024 + (size_t)(r0 + r)) * 1024;
#pragma unroll
        for (int t = 0; t < 4; ++t) {
            f32x4 o;
            o[0] = fmaxf(zz[rw][4 * t + 0] - tau[rw], 0.f);
            o[1] = fmaxf(zz[rw][4 * t + 1] - tau[rw], 0.f);
            o[2] = fmaxf(zz[rw][4 * t + 2] - tau[rw], 0.f);
            o[3] = fmaxf(zz[rw][4 * t + 3] - tau[rw], 0.f);
            __builtin_nontemporal_store(o, (f32x4*)&orow[(ln << 2) + (t << 8)]);
        }
    }
}

// ---------------------------------------------------------------------------
extern "C" void kernel_launch(void* const* d_in, const int* in_sizes, int n_in,
                              void* d_out, int out_size, void* d_ws, size_t ws_size,
                              hipStream_t stream) {
    const float* x = (const float*)d_in[0];          // [4096, 1024]
    const float* w = (const float*)d_in[1];          // [3072, 1024]
    float* out = (float*)d_out;                      // [64, 1024, 1024]

    const size_t HE = (size_t)64 * 1024 * 64;        // 4.19M elems per head buf
    const size_t XE = (size_t)4096 * 1024;           // x elems
    const size_t WE = (size_t)2048 * 1024;           // W' elems (rows 1024..3071)
    ushort* khi = (ushort*)d_ws;
    ushort* klo = khi + HE;
    ushort* qhi = klo + HE;
    ushort* qlo = qhi + HE;
    ushort* xh  = qlo + HE;
    ushort* xl  = xh + XE;
    ushort* wh  = xl + XE;
    ushort* wl  = wh + WE;                           // total ~58.7 MB of d_ws

    convert_split_kernel<<<2048, 256, 0, stream>>>(x, xh, xl, (int)(XE / 4));
    convert_split_kernel<<<2048, 256, 0, stream>>>(w + (size_t)1024 * 1024, wh, wl, (int)(WE / 4));
    proj_kernel<<<dim3(16, 32), 512, 0, stream>>>(xh, xl, wh, wl, khi, klo, qhi, qlo);
    attn_sparsemax_kernel<<<dim3(64, 64), 512, 0, stream>>>(khi, klo, qhi, qlo, out);
}